// Round 1
// baseline (3457.071 us; speedup 1.0000x reference)
//
#include <hip/hip_runtime.h>

typedef _Float16 half8 __attribute__((ext_vector_type(8)));
typedef float floatx4 __attribute__((ext_vector_type(4)));

#define N_IN   128
#define N_HID  1024
#define N_OUT  64
#define BB     128
#define TT     256

#define WHH_STRIDE 1032   // 1024 + 8 halves pad (stride%32 words = 4 -> 2-way, free)
#define WIN_STRIDE 136    // 128 + 8
#define RED_STRIDE 33

__device__ __forceinline__ float tanh_fast(float v) {
    float e = __expf(2.0f * v);
    return 1.0f - 2.0f / (e + 1.0f);
}

// Persistent sequential RNN kernel.
// Grid: 256 blocks = 8 batch-groups (16 rows each) x 32 hidden-slices (32 cols each).
// group = bid & 7 (XCD round-robin heuristic keeps a group's exchange XCD-local).
// W_hh/W_in slice resident in LDS as fp16 hi + (fp16 lo * 1024) for near-fp32 accuracy.
__global__ __launch_bounds__(256) void rnn_seq_kernel(
    const float* __restrict__ x,        // [128][256][128]
    const float* __restrict__ h0,       // [128][1024]
    const float* __restrict__ w_in,     // [1024][128]
    const float* __restrict__ w_hh,     // [1024][1024]
    const float* __restrict__ w_hh_b,   // [1024]
    const float* __restrict__ alpha,    // [1024]
    const float* __restrict__ noise_raw,// [128][1024]
    const int* __restrict__ pt_ptr,     // scalar
    float* __restrict__ out,            // full output buffer (hidden_list | output_list | h_final)
    _Float16* __restrict__ actbuf,      // d_ws: 2 x [128][1024] fp16 (parity double-buffer)
    unsigned int* __restrict__ cnt)     // d_ws: [257][8] arrival counters
{
    __shared__ _Float16 Whh_hi[32 * WHH_STRIDE];
    __shared__ _Float16 Whh_lo[32 * WHH_STRIDE];
    __shared__ _Float16 Win_hi[32 * WIN_STRIDE];
    __shared__ _Float16 Win_lo[32 * WIN_STRIDE];
    __shared__ float red[4 * 16 * RED_STRIDE];

    const int tid  = threadIdx.x;
    const int bid  = blockIdx.x;
    const int g    = bid & 7;    // batch group
    const int s    = bid >> 3;   // hidden slice
    const int w    = tid >> 6;   // wave 0..3 (K-split)
    const int lane = tid & 63;
    const int quad = lane >> 4;
    const int mrow = lane & 15;

    // ---- stage W_hh slice rows [32s, 32s+32) as split fp16 ----
    for (int p = 0; p < 32; ++p) {
        int f4 = tid + (p << 8);
        int c  = f4 >> 8;
        int k4 = (f4 & 255) << 2;
        floatx4 wv = *(const floatx4*)(w_hh + ((size_t)(s * 32 + c) << 10) + k4);
        #pragma unroll
        for (int i = 0; i < 4; ++i) {
            float v = wv[i];
            _Float16 hi = (_Float16)v;
            _Float16 lo = (_Float16)((v - (float)hi) * 1024.0f); // scale keeps lo normal in fp16
            Whh_hi[c * WHH_STRIDE + k4 + i] = hi;
            Whh_lo[c * WHH_STRIDE + k4 + i] = lo;
        }
    }
    // ---- stage W_in slice ----
    for (int p = 0; p < 4; ++p) {
        int f4 = tid + (p << 8);
        int c  = f4 >> 5;
        int k4 = (f4 & 31) << 2;
        floatx4 wv = *(const floatx4*)(w_in + ((size_t)(s * 32 + c) << 7) + k4);
        #pragma unroll
        for (int i = 0; i < 4; ++i) {
            float v = wv[i];
            _Float16 hi = (_Float16)v;
            _Float16 lo = (_Float16)((v - (float)hi) * 1024.0f);
            Win_hi[c * WIN_STRIDE + k4 + i] = hi;
            Win_lo[c * WIN_STRIDE + k4 + i] = lo;
        }
    }

    // ---- per-thread owned state: same col j, rows r0 and r0+8 of the group ----
    const int col = tid & 31;
    const int jg  = s * 32 + col;
    const int r0  = tid >> 5;          // 0..7
    const int b0g = g * 16 + r0;
    const int b1g = b0g + 8;
    const float a_j    = alpha[jg];
    const float bias_j = w_hh_b[jg];
    const float om_a   = 1.0f - a_j;
    const int pt = *pt_ptr;
    float hA = h0[((size_t)b0g << 10) + jg];
    float hB = h0[((size_t)b1g << 10) + jg];

    // act_{-1} = tanh(h0) into parity-1 buffer
    {
        _Float16* act1 = actbuf + BB * N_HID;
        act1[(b0g << 10) + jg] = (_Float16)tanh_fast(hA);
        act1[(b1g << 10) + jg] = (_Float16)tanh_fast(hB);
    }
    __syncthreads();
    if (tid == 0) {
        __threadfence();
        __hip_atomic_fetch_add(&cnt[g], 1u, __ATOMIC_RELEASE, __HIP_MEMORY_SCOPE_AGENT);
    }

    float* hidden_list = out;
    float* h_final = out + (size_t)BB * TT * N_HID + (size_t)BB * TT * N_OUT;
    const int arow = g * 16 + mrow;    // A-fragment batch row for this lane

    for (int t = 0; t < TT; ++t) {
        // ---- wait for act_{t-1} from all 32 slice-blocks of this group ----
        if (tid == 0) {
            while (__hip_atomic_load(&cnt[(size_t)t * 8 + g], __ATOMIC_RELAXED,
                                     __HIP_MEMORY_SCOPE_AGENT) < 32u) {
                __builtin_amdgcn_s_sleep(1);
            }
            (void)__hip_atomic_load(&cnt[(size_t)t * 8 + g], __ATOMIC_ACQUIRE,
                                    __HIP_MEMORY_SCOPE_AGENT);
        }
        __syncthreads();

        const _Float16* actr = actbuf + (size_t)((t & 1) ^ 1) * (BB * N_HID);

        // A fragments: activations, wave covers k in [w*256, w*256+256)
        half8 afr[8];
        {
            const _Float16* abase = actr + ((size_t)arow << 10) + (w << 8) + (quad << 3);
            #pragma unroll
            for (int kc = 0; kc < 8; ++kc)
                afr[kc] = *(const half8*)(abase + kc * 32);
        }
        // A fragment: x_t, wave covers k in [w*32, w*32+32)
        half8 xfr;
        {
            const float* xp = x + (((size_t)arow << 8) + t) * N_IN + (w << 5) + (quad << 3);
            floatx4 x0 = *(const floatx4*)xp;
            floatx4 x1 = *(const floatx4*)(xp + 4);
            #pragma unroll
            for (int i = 0; i < 4; ++i) { xfr[i] = (_Float16)x0[i]; xfr[4 + i] = (_Float16)x1[i]; }
        }

        floatx4 acch0 = {0.f,0.f,0.f,0.f}, acch1 = {0.f,0.f,0.f,0.f};
        floatx4 accl0 = {0.f,0.f,0.f,0.f}, accl1 = {0.f,0.f,0.f,0.f};

        // input projection (K=32 per wave)
        {
            int kb = (w << 5) + (quad << 3);
            const half8 b0h = *(const half8*)&Win_hi[(mrow)      * WIN_STRIDE + kb];
            const half8 b0l = *(const half8*)&Win_lo[(mrow)      * WIN_STRIDE + kb];
            const half8 b1h = *(const half8*)&Win_hi[(16 + mrow) * WIN_STRIDE + kb];
            const half8 b1l = *(const half8*)&Win_lo[(16 + mrow) * WIN_STRIDE + kb];
            acch0 = __builtin_amdgcn_mfma_f32_16x16x32_f16(xfr, b0h, acch0, 0, 0, 0);
            accl0 = __builtin_amdgcn_mfma_f32_16x16x32_f16(xfr, b0l, accl0, 0, 0, 0);
            acch1 = __builtin_amdgcn_mfma_f32_16x16x32_f16(xfr, b1h, acch1, 0, 0, 0);
            accl1 = __builtin_amdgcn_mfma_f32_16x16x32_f16(xfr, b1l, accl1, 0, 0, 0);
        }
        // recurrent projection (K=256 per wave)
        #pragma unroll
        for (int kc = 0; kc < 8; ++kc) {
            int kb = (w << 8) + (kc << 5) + (quad << 3);
            const half8 b0h = *(const half8*)&Whh_hi[(mrow)      * WHH_STRIDE + kb];
            const half8 b0l = *(const half8*)&Whh_lo[(mrow)      * WHH_STRIDE + kb];
            const half8 b1h = *(const half8*)&Whh_hi[(16 + mrow) * WHH_STRIDE + kb];
            const half8 b1l = *(const half8*)&Whh_lo[(16 + mrow) * WHH_STRIDE + kb];
            acch0 = __builtin_amdgcn_mfma_f32_16x16x32_f16(afr[kc], b0h, acch0, 0, 0, 0);
            accl0 = __builtin_amdgcn_mfma_f32_16x16x32_f16(afr[kc], b0l, accl0, 0, 0, 0);
            acch1 = __builtin_amdgcn_mfma_f32_16x16x32_f16(afr[kc], b1h, acch1, 0, 0, 0);
            accl1 = __builtin_amdgcn_mfma_f32_16x16x32_f16(afr[kc], b1l, accl1, 0, 0, 0);
        }

        // combine hi + lo/1024, cross-wave partial write (D: row=quad*4+r, col=lane&15)
        #pragma unroll
        for (int r = 0; r < 4; ++r) {
            red[(w * 16 + quad * 4 + r) * RED_STRIDE + mrow]
                = acch0[r] + accl0[r] * (1.0f / 1024.0f);
            red[(w * 16 + quad * 4 + r) * RED_STRIDE + 16 + mrow]
                = acch1[r] + accl1[r] * (1.0f / 1024.0f);
        }
        __syncthreads();

        // reduce 4 wave-partials, leaky update, noise, stores
        float t0v = bias_j, t1v = bias_j;
        #pragma unroll
        for (int ww = 0; ww < 4; ++ww) {
            t0v += red[(ww * 16 + r0)     * RED_STRIDE + col];
            t1v += red[(ww * 16 + r0 + 8) * RED_STRIDE + col];
        }
        hA = om_a * hA + a_j * t0v;
        hB = om_a * hB + a_j * t1v;
        if (t == pt) {
            float sc = 0.05f * __builtin_sqrtf(a_j);
            hA += noise_raw[((size_t)b0g << 10) + jg] * sc;
            hB += noise_raw[((size_t)b1g << 10) + jg] * sc;
        }
        hidden_list[(((size_t)b0g << 8) + t) * N_HID + jg] = hA;
        hidden_list[(((size_t)b1g << 8) + t) * N_HID + jg] = hB;
        _Float16* actw = actbuf + (size_t)(t & 1) * (BB * N_HID);
        actw[(b0g << 10) + jg] = (_Float16)tanh_fast(hA);
        actw[(b1g << 10) + jg] = (_Float16)tanh_fast(hB);

        __syncthreads();   // drains all block stores (vmcnt(0) before s_barrier)
        if (tid == 0) {
            __threadfence();  // agent release: L2 writeback so other XCDs can see act
            __hip_atomic_fetch_add(&cnt[(size_t)(t + 1) * 8 + g], 1u,
                                   __ATOMIC_RELEASE, __HIP_MEMORY_SCOPE_AGENT);
        }
    }

    h_final[((size_t)b0g << 10) + jg] = hA;
    h_final[((size_t)b1g << 10) + jg] = hB;
}

// output_list[b,t,:] = hidden_list[b,t,:] @ w_out^T  — parallel fp16 MFMA GEMM,
// M = 32768 flat (b,t) rows, N = 64, K = 1024. 512 blocks x 64 rows.
__global__ __launch_bounds__(256) void out_gemm_kernel(
    const float* __restrict__ hl,
    const float* __restrict__ w_out,
    float* __restrict__ outp)
{
    __shared__ _Float16 Wb[64 * 264];  // [n][kchunk 256], pad +8
    const int tid  = threadIdx.x;
    const int w    = tid >> 6;
    const int lane = tid & 63;
    const int quad = lane >> 4;
    const int mrow = lane & 15;
    const size_t rowbase = (size_t)blockIdx.x << 6;

    floatx4 acc0 = {0.f,0.f,0.f,0.f}, acc1 = {0.f,0.f,0.f,0.f};
    floatx4 acc2 = {0.f,0.f,0.f,0.f}, acc3 = {0.f,0.f,0.f,0.f};

    for (int kc = 0; kc < 4; ++kc) {
        __syncthreads();
        // stage w_out[:, kc*256 .. +256) as fp16
        for (int p = 0; p < 16; ++p) {
            int f4 = tid + (p << 8);
            int n  = f4 >> 6;
            int k4 = (f4 & 63) << 2;
            floatx4 wv = *(const floatx4*)(w_out + ((size_t)n << 10) + (kc << 8) + k4);
            #pragma unroll
            for (int i = 0; i < 4; ++i) Wb[n * 264 + k4 + i] = (_Float16)wv[i];
        }
        __syncthreads();
        for (int kk = 0; kk < 8; ++kk) {
            const float* ap = hl + (rowbase + (w << 4) + mrow) * 1024
                                 + (kc << 8) + (kk << 5) + (quad << 3);
            floatx4 a0v = *(const floatx4*)ap;
            floatx4 a1v = *(const floatx4*)(ap + 4);
            half8 afr;
            #pragma unroll
            for (int i = 0; i < 4; ++i) { afr[i] = (_Float16)a0v[i]; afr[4 + i] = (_Float16)a1v[i]; }
            int kb = (kk << 5) + (quad << 3);
            half8 bf0 = *(const half8*)&Wb[(mrow)      * 264 + kb];
            half8 bf1 = *(const half8*)&Wb[(16 + mrow) * 264 + kb];
            half8 bf2 = *(const half8*)&Wb[(32 + mrow) * 264 + kb];
            half8 bf3 = *(const half8*)&Wb[(48 + mrow) * 264 + kb];
            acc0 = __builtin_amdgcn_mfma_f32_16x16x32_f16(afr, bf0, acc0, 0, 0, 0);
            acc1 = __builtin_amdgcn_mfma_f32_16x16x32_f16(afr, bf1, acc1, 0, 0, 0);
            acc2 = __builtin_amdgcn_mfma_f32_16x16x32_f16(afr, bf2, acc2, 0, 0, 0);
            acc3 = __builtin_amdgcn_mfma_f32_16x16x32_f16(afr, bf3, acc3, 0, 0, 0);
        }
    }
    size_t rb = rowbase + (w << 4);
    #pragma unroll
    for (int r = 0; r < 4; ++r) {
        outp[(rb + quad * 4 + r) * 64 +      mrow] = acc0[r];
        outp[(rb + quad * 4 + r) * 64 + 16 + mrow] = acc1[r];
        outp[(rb + quad * 4 + r) * 64 + 32 + mrow] = acc2[r];
        outp[(rb + quad * 4 + r) * 64 + 48 + mrow] = acc3[r];
    }
}

extern "C" void kernel_launch(void* const* d_in, const int* in_sizes, int n_in,
                              void* d_out, int out_size, void* d_ws, size_t ws_size,
                              hipStream_t stream)
{
    const float* x      = (const float*)d_in[0];
    const float* h0     = (const float*)d_in[1];
    const float* w_in   = (const float*)d_in[2];
    const float* w_hh   = (const float*)d_in[3];
    const float* w_hh_b = (const float*)d_in[4];
    const float* w_out  = (const float*)d_in[5];
    const float* alpha  = (const float*)d_in[6];
    const float* noise  = (const float*)d_in[7];
    const int*   pt     = (const int*)d_in[8];
    float* out = (float*)d_out;

    _Float16* actbuf = (_Float16*)d_ws;
    unsigned int* cnt =
        (unsigned int*)((char*)d_ws + (size_t)2 * BB * N_HID * sizeof(_Float16));

    // counters are re-poisoned to 0xAA before every launch -> zero them on-stream
    hipMemsetAsync(cnt, 0, 257 * 8 * sizeof(unsigned int), stream);

    hipLaunchKernelGGL(rnn_seq_kernel, dim3(256), dim3(256), 0, stream,
                       x, h0, w_in, w_hh, w_hh_b, alpha, noise, pt, out, actbuf, cnt);

    float* output_list = out + (size_t)BB * TT * N_HID;
    hipLaunchKernelGGL(out_gemm_kernel, dim3(512), dim3(256), 0, stream,
                       out, w_out, output_list);
}

// Round 2
// 1202.357 us; speedup vs baseline: 2.8752x; 2.8752x over previous
//
#include <hip/hip_runtime.h>

typedef _Float16 half8 __attribute__((ext_vector_type(8)));
typedef float floatx4 __attribute__((ext_vector_type(4)));
typedef float floatx2 __attribute__((ext_vector_type(2)));

#define N_IN   128
#define N_HID  1024
#define N_OUT  64
#define BB     128
#define TT     256

#define WHH_STRIDE 1032   // 1024 + 8 halves pad
#define WIN_STRIDE 136    // 128 + 8
#define RED_STRIDE 33

__device__ __forceinline__ float tanh_fast(float v) {
    float e = __expf(2.0f * v);
    return 1.0f - 2.0f / (e + 1.0f);
}

// Persistent sequential RNN kernel, fence-free sync protocol.
// Grid: 256 blocks = 8 batch-groups (16 rows) x 32 hidden-slices (32 cols).
// All cross-block traffic (act exchange + flags) uses relaxed AGENT-scope
// atomics -> coherent at MALL, works for ANY block->XCD placement, and never
// emits buffer_wbl2/buffer_inv (the 13 us/step killer of R0).
// Weights live in REGISTERS (loaded once from LDS staging); the dead LDS
// arrays still pin occupancy to 1 block/CU so all 256 blocks are co-resident.
__global__ __launch_bounds__(256, 1) void rnn_seq_kernel(
    const float* __restrict__ x,        // [128][256][128]
    const float* __restrict__ h0,       // [128][1024]
    const float* __restrict__ w_in,     // [1024][128]
    const float* __restrict__ w_hh,     // [1024][1024]
    const float* __restrict__ w_hh_b,   // [1024]
    const float* __restrict__ alpha,    // [1024]
    const float* __restrict__ noise_raw,// [128][1024]
    const int* __restrict__ pt_ptr,     // scalar
    float* __restrict__ out,            // hidden_list | output_list | h_final
    _Float16* __restrict__ actbuf,      // d_ws: 2 x [128][1024] fp16 parity buffers
    unsigned int* __restrict__ flags)   // d_ws: [257][8][32] token flags (no init needed)
{
    __shared__ _Float16 Whh_hi[32 * WHH_STRIDE];
    __shared__ _Float16 Whh_lo[32 * WHH_STRIDE];
    __shared__ _Float16 Win_hi[32 * WIN_STRIDE];
    __shared__ _Float16 Win_lo[32 * WIN_STRIDE];
    __shared__ float red[4 * 16 * RED_STRIDE];

    const int tid  = threadIdx.x;
    const int bid  = blockIdx.x;
    const int g    = bid & 7;    // batch group
    const int s    = bid >> 3;   // hidden slice
    const int w    = tid >> 6;   // wave 0..3 (K-split)
    const int lane = tid & 63;
    const int quad = lane >> 4;
    const int mrow = lane & 15;

    // ---- stage W_hh slice rows [32s, 32s+32) as split fp16 hi + lo*1024 ----
    for (int p = 0; p < 32; ++p) {
        int f4 = tid + (p << 8);
        int c  = f4 >> 8;
        int k4 = (f4 & 255) << 2;
        floatx4 wv = *(const floatx4*)(w_hh + ((size_t)(s * 32 + c) << 10) + k4);
        #pragma unroll
        for (int i = 0; i < 4; ++i) {
            float v = wv[i];
            _Float16 hi = (_Float16)v;
            _Float16 lo = (_Float16)((v - (float)hi) * 1024.0f);
            Whh_hi[c * WHH_STRIDE + k4 + i] = hi;
            Whh_lo[c * WHH_STRIDE + k4 + i] = lo;
        }
    }
    for (int p = 0; p < 4; ++p) {
        int f4 = tid + (p << 8);
        int c  = f4 >> 5;
        int k4 = (f4 & 31) << 2;
        floatx4 wv = *(const floatx4*)(w_in + ((size_t)(s * 32 + c) << 7) + k4);
        #pragma unroll
        for (int i = 0; i < 4; ++i) {
            float v = wv[i];
            _Float16 hi = (_Float16)v;
            _Float16 lo = (_Float16)((v - (float)hi) * 1024.0f);
            Win_hi[c * WIN_STRIDE + k4 + i] = hi;
            Win_lo[c * WIN_STRIDE + k4 + i] = lo;
        }
    }
    __syncthreads();

    // ---- load this lane's B-fragments into registers (LDS never re-read) ----
    half8 bh0[8], bl0[8], bh1[8], bl1[8];
    #pragma unroll
    for (int kc = 0; kc < 8; ++kc) {
        int kb = (w << 8) + (kc << 5) + (quad << 3);
        bh0[kc] = *(const half8*)&Whh_hi[mrow * WHH_STRIDE + kb];
        bl0[kc] = *(const half8*)&Whh_lo[mrow * WHH_STRIDE + kb];
        bh1[kc] = *(const half8*)&Whh_hi[(16 + mrow) * WHH_STRIDE + kb];
        bl1[kc] = *(const half8*)&Whh_lo[(16 + mrow) * WHH_STRIDE + kb];
    }
    half8 wi_h0, wi_l0, wi_h1, wi_l1;
    {
        int kb = (w << 5) + (quad << 3);
        wi_h0 = *(const half8*)&Win_hi[mrow * WIN_STRIDE + kb];
        wi_l0 = *(const half8*)&Win_lo[mrow * WIN_STRIDE + kb];
        wi_h1 = *(const half8*)&Win_hi[(16 + mrow) * WIN_STRIDE + kb];
        wi_l1 = *(const half8*)&Win_lo[(16 + mrow) * WIN_STRIDE + kb];
    }

    // ---- per-thread owned state: row b, two adjacent cols j0,j0+1 ----
    const int r   = tid >> 4;          // 0..15 group-row
    const int c2  = tid & 15;          // col pair
    const int b   = g * 16 + r;
    const int j0  = s * 32 + 2 * c2;
    const floatx2 a2  = *(const floatx2*)&alpha[j0];
    const floatx2 bi2 = *(const floatx2*)&w_hh_b[j0];
    const floatx2 nr2 = *(const floatx2*)&noise_raw[((size_t)b << 10) + j0];
    const float n0 = nr2.x * 0.05f * __builtin_sqrtf(a2.x);
    const float n1 = nr2.y * 0.05f * __builtin_sqrtf(a2.y);
    const int pt = *pt_ptr;
    floatx2 h2 = *(const floatx2*)&h0[((size_t)b << 10) + j0];
    float hA = h2.x, hB = h2.y;

    // act_{-1} = tanh(h0) into parity-1 buffer (coherent store)
    {
        unsigned int* act1_32 = (unsigned int*)(actbuf + BB * N_HID);
        union { _Float16 h[2]; unsigned int u; } pk;
        pk.h[0] = (_Float16)tanh_fast(hA);
        pk.h[1] = (_Float16)tanh_fast(hB);
        __hip_atomic_store(&act1_32[(((unsigned)b << 10) + j0) >> 1], pk.u,
                           __ATOMIC_RELAXED, __HIP_MEMORY_SCOPE_AGENT);
    }
    __syncthreads();   // emits s_waitcnt vmcnt(0) -> all act stores complete
    if (tid == 0)
        __hip_atomic_store(&flags[((unsigned)g) * 32u + s], 1u,
                           __ATOMIC_RELAXED, __HIP_MEMORY_SCOPE_AGENT);

    float* hidden_list = out;
    float* h_final = out + (size_t)BB * TT * N_HID + (size_t)BB * TT * N_OUT;
    const int arow = g * 16 + mrow;    // A-fragment batch row for this lane

    for (int t = 0; t < TT; ++t) {
        // ---- wave w waits only for its 8 producer slices [8w, 8w+8) ----
        {
            const unsigned tok = (unsigned)t + 1u;
            const unsigned fidx = ((unsigned)t * 8u + g) * 32u + (w << 3) + (lane & 7);
            while (true) {
                unsigned v = __hip_atomic_load(&flags[fidx], __ATOMIC_RELAXED,
                                               __HIP_MEMORY_SCOPE_AGENT);
                if (__ballot(v == tok) == ~0ull) break;
                __builtin_amdgcn_s_sleep(1);
            }
        }

        // A fragments: activations (coherent 8B loads), k in [w*256, w*256+256)
        half8 afr[8];
        {
            const unsigned long long* actq = (const unsigned long long*)
                (actbuf + (size_t)((t & 1) ^ 1) * (BB * N_HID));
            const unsigned long long* p =
                actq + ((((size_t)arow << 10) + (w << 8) + (quad << 3)) >> 2);
            #pragma unroll
            for (int kc = 0; kc < 8; ++kc) {
                union { unsigned long long u[2]; half8 h; } cv;
                cv.u[0] = __hip_atomic_load(p + kc * 8,     __ATOMIC_RELAXED,
                                            __HIP_MEMORY_SCOPE_AGENT);
                cv.u[1] = __hip_atomic_load(p + kc * 8 + 1, __ATOMIC_RELAXED,
                                            __HIP_MEMORY_SCOPE_AGENT);
                afr[kc] = cv.h;
            }
        }
        // A fragment: x_t (pristine input, plain loads), k in [w*32, w*32+32)
        half8 xfr;
        {
            const float* xp = x + (((size_t)arow << 8) + t) * N_IN + (w << 5) + (quad << 3);
            floatx4 x0 = *(const floatx4*)xp;
            floatx4 x1 = *(const floatx4*)(xp + 4);
            #pragma unroll
            for (int i = 0; i < 4; ++i) { xfr[i] = (_Float16)x0[i]; xfr[4 + i] = (_Float16)x1[i]; }
        }

        floatx4 acch0 = {0.f,0.f,0.f,0.f}, acch1 = {0.f,0.f,0.f,0.f};
        floatx4 accl0 = {0.f,0.f,0.f,0.f}, accl1 = {0.f,0.f,0.f,0.f};

        acch0 = __builtin_amdgcn_mfma_f32_16x16x32_f16(xfr, wi_h0, acch0, 0, 0, 0);
        accl0 = __builtin_amdgcn_mfma_f32_16x16x32_f16(xfr, wi_l0, accl0, 0, 0, 0);
        acch1 = __builtin_amdgcn_mfma_f32_16x16x32_f16(xfr, wi_h1, acch1, 0, 0, 0);
        accl1 = __builtin_amdgcn_mfma_f32_16x16x32_f16(xfr, wi_l1, accl1, 0, 0, 0);

        #pragma unroll
        for (int kc = 0; kc < 8; ++kc) {
            acch0 = __builtin_amdgcn_mfma_f32_16x16x32_f16(afr[kc], bh0[kc], acch0, 0, 0, 0);
            accl0 = __builtin_amdgcn_mfma_f32_16x16x32_f16(afr[kc], bl0[kc], accl0, 0, 0, 0);
            acch1 = __builtin_amdgcn_mfma_f32_16x16x32_f16(afr[kc], bh1[kc], acch1, 0, 0, 0);
            accl1 = __builtin_amdgcn_mfma_f32_16x16x32_f16(afr[kc], bl1[kc], accl1, 0, 0, 0);
        }

        // cross-wave partials (D layout: row=quad*4+rr, col=lane&15)
        #pragma unroll
        for (int rr = 0; rr < 4; ++rr) {
            red[(w * 16 + quad * 4 + rr) * RED_STRIDE + mrow]
                = acch0[rr] + accl0[rr] * (1.0f / 1024.0f);
            red[(w * 16 + quad * 4 + rr) * RED_STRIDE + 16 + mrow]
                = acch1[rr] + accl1[rr] * (1.0f / 1024.0f);
        }
        __syncthreads();

        // reduce 4 wave-partials, leaky update, noise, stores
        float t0v = bi2.x, t1v = bi2.y;
        #pragma unroll
        for (int ww = 0; ww < 4; ++ww) {
            t0v += red[(ww * 16 + r) * RED_STRIDE + 2 * c2];
            t1v += red[(ww * 16 + r) * RED_STRIDE + 2 * c2 + 1];
        }
        hA = (1.0f - a2.x) * hA + a2.x * t0v;
        hB = (1.0f - a2.y) * hB + a2.y * t1v;
        if (t == pt) { hA += n0; hB += n1; }

        floatx2 hv = {hA, hB};
        *(floatx2*)&hidden_list[(((size_t)b << 8) + t) * N_HID + j0] = hv;

        {
            union { _Float16 h[2]; unsigned int u; } pk;
            pk.h[0] = (_Float16)tanh_fast(hA);
            pk.h[1] = (_Float16)tanh_fast(hB);
            unsigned int* actw32 = (unsigned int*)(actbuf + (size_t)(t & 1) * (BB * N_HID));
            __hip_atomic_store(&actw32[(((unsigned)b << 10) + j0) >> 1], pk.u,
                               __ATOMIC_RELAXED, __HIP_MEMORY_SCOPE_AGENT);
        }

        __syncthreads();   // drains vmcnt: act stores complete before flag store
        if (tid == 0)
            __hip_atomic_store(&flags[((unsigned)(t + 1) * 8u + g) * 32u + s],
                               (unsigned)t + 2u,
                               __ATOMIC_RELAXED, __HIP_MEMORY_SCOPE_AGENT);
    }

    *(floatx2*)&h_final[((size_t)b << 10) + j0] = (floatx2){hA, hB};
}

// output_list[b,t,:] = hidden_list[b,t,:] @ w_out^T  — parallel fp16 MFMA GEMM,
// M = 32768 flat (b,t) rows, N = 64, K = 1024. 512 blocks x 64 rows.
__global__ __launch_bounds__(256) void out_gemm_kernel(
    const float* __restrict__ hl,
    const float* __restrict__ w_out,
    float* __restrict__ outp)
{
    __shared__ _Float16 Wb[64 * 264];
    const int tid  = threadIdx.x;
    const int w    = tid >> 6;
    const int lane = tid & 63;
    const int quad = lane >> 4;
    const int mrow = lane & 15;
    const size_t rowbase = (size_t)blockIdx.x << 6;

    floatx4 acc0 = {0.f,0.f,0.f,0.f}, acc1 = {0.f,0.f,0.f,0.f};
    floatx4 acc2 = {0.f,0.f,0.f,0.f}, acc3 = {0.f,0.f,0.f,0.f};

    for (int kc = 0; kc < 4; ++kc) {
        __syncthreads();
        for (int p = 0; p < 16; ++p) {
            int f4 = tid + (p << 8);
            int n  = f4 >> 6;
            int k4 = (f4 & 63) << 2;
            floatx4 wv = *(const floatx4*)(w_out + ((size_t)n << 10) + (kc << 8) + k4);
            #pragma unroll
            for (int i = 0; i < 4; ++i) Wb[n * 264 + k4 + i] = (_Float16)wv[i];
        }
        __syncthreads();
        for (int kk = 0; kk < 8; ++kk) {
            const float* ap = hl + (rowbase + (w << 4) + mrow) * 1024
                                 + (kc << 8) + (kk << 5) + (quad << 3);
            floatx4 a0v = *(const floatx4*)ap;
            floatx4 a1v = *(const floatx4*)(ap + 4);
            half8 afr;
            #pragma unroll
            for (int i = 0; i < 4; ++i) { afr[i] = (_Float16)a0v[i]; afr[4 + i] = (_Float16)a1v[i]; }
            int kb = (kk << 5) + (quad << 3);
            half8 bf0 = *(const half8*)&Wb[(mrow)      * 264 + kb];
            half8 bf1 = *(const half8*)&Wb[(16 + mrow) * 264 + kb];
            half8 bf2 = *(const half8*)&Wb[(32 + mrow) * 264 + kb];
            half8 bf3 = *(const half8*)&Wb[(48 + mrow) * 264 + kb];
            acc0 = __builtin_amdgcn_mfma_f32_16x16x32_f16(afr, bf0, acc0, 0, 0, 0);
            acc1 = __builtin_amdgcn_mfma_f32_16x16x32_f16(afr, bf1, acc1, 0, 0, 0);
            acc2 = __builtin_amdgcn_mfma_f32_16x16x32_f16(afr, bf2, acc2, 0, 0, 0);
            acc3 = __builtin_amdgcn_mfma_f32_16x16x32_f16(afr, bf3, acc3, 0, 0, 0);
        }
    }
    size_t rb = rowbase + (w << 4);
    #pragma unroll
    for (int rr = 0; rr < 4; ++rr) {
        outp[(rb + quad * 4 + rr) * 64 +      mrow] = acc0[rr];
        outp[(rb + quad * 4 + rr) * 64 + 16 + mrow] = acc1[rr];
        outp[(rb + quad * 4 + rr) * 64 + 32 + mrow] = acc2[rr];
        outp[(rb + quad * 4 + rr) * 64 + 48 + mrow] = acc3[rr];
    }
}

extern "C" void kernel_launch(void* const* d_in, const int* in_sizes, int n_in,
                              void* d_out, int out_size, void* d_ws, size_t ws_size,
                              hipStream_t stream)
{
    const float* x      = (const float*)d_in[0];
    const float* h0     = (const float*)d_in[1];
    const float* w_in   = (const float*)d_in[2];
    const float* w_hh   = (const float*)d_in[3];
    const float* w_hh_b = (const float*)d_in[4];
    const float* w_out  = (const float*)d_in[5];
    const float* alpha  = (const float*)d_in[6];
    const float* noise  = (const float*)d_in[7];
    const int*   pt     = (const int*)d_in[8];
    float* out = (float*)d_out;

    _Float16* actbuf = (_Float16*)d_ws;
    // token-flag array: written once per (t,g,s) with value t+1; 0xAA poison
    // never collides with a token, so NO memset/zeroing is needed.
    unsigned int* flags =
        (unsigned int*)((char*)d_ws + (size_t)2 * BB * N_HID * sizeof(_Float16));

    hipLaunchKernelGGL(rnn_seq_kernel, dim3(256), dim3(256), 0, stream,
                       x, h0, w_in, w_hh, w_hh_b, alpha, noise, pt, out, actbuf, flags);

    float* output_list = out + (size_t)BB * TT * N_HID;
    hipLaunchKernelGGL(out_gemm_kernel, dim3(512), dim3(256), 0, stream,
                       out, w_out, output_list);
}